// Round 16
// baseline (368.758 us; speedup 1.0000x reference)
//
#include <hip/hip_runtime.h>
#include <hip/hip_bf16.h>

#define LL 4096
#define DD 1024
#define NB 4
#define N4 4096          // complex FFT size (packs 8192 reals)
#define KBINS 4097       // real-spectrum bins of the 8192-pt transform
#define NSLOT4 4366      // SLT(4095)+1
#define PI_F 3.14159265358979323846f
#define INV4 (1.0f / 4096.0f)

typedef __attribute__((ext_vector_type(4))) float f32x4;
typedef __attribute__((ext_vector_type(8))) short s16x8;

#if defined(__has_builtin)
#if __has_builtin(__builtin_amdgcn_global_load_lds)
#define USE_GLOAD_LDS 1
#endif
#endif
#ifndef USE_GLOAD_LDS
#define USE_GLOAD_LDS 0
#endif

__device__ __forceinline__ unsigned short f2bf(float f) {
  unsigned int x = __float_as_uint(f);
  x += 0x7fffu + ((x >> 16) & 1u);
  return (unsigned short)(x >> 16);
}

// padded LDS slot: 64-stride (bit-rev scatter) lands ~2-way, radix strides spread
__device__ __forceinline__ int SLT(int n) { return n + (n >> 4) + (n >> 8); }
__device__ __forceinline__ int brev12(int n) { return (int)(__brev((unsigned)n) >> 20); }

__device__ __forceinline__ float2 cmul(float2 a, float2 b) {
  return make_float2(a.x * b.x - a.y * b.y, a.x * b.y + a.y * b.x);
}
__device__ __forceinline__ float2 cadd(float2 a, float2 b) { return make_float2(a.x + b.x, a.y + b.y); }
__device__ __forceinline__ float2 csub(float2 a, float2 b) { return make_float2(a.x - b.x, a.y - b.y); }
__device__ __forceinline__ float2 conjf(float2 a) { return make_float2(a.x, -a.y); }
__device__ __forceinline__ float2 mulni(float2 v) { return make_float2(v.y, -v.x); }   // * -i
__device__ __forceinline__ float2 mulpi(float2 v) { return make_float2(-v.y, v.x); }   // * +i

// ------------------------------------------------ radix-8 butterfly (verified r5-r15)
template<bool INV>
__device__ __forceinline__ void bfly8(float2& A0, float2& A1, float2& A2, float2& A3,
                                      float2& A4, float2& A5, float2& A6, float2& A7,
                                      float2 w1, float2 w2, float2 w3) {
  const float C8 = 0.70710678118654752f;
  float2 t;
  t = cmul(w1, A1); float2 b0 = cadd(A0, t), b1 = csub(A0, t);
  t = cmul(w1, A3); float2 b2 = cadd(A2, t), b3 = csub(A2, t);
  t = cmul(w1, A5); float2 b4 = cadd(A4, t), b5 = csub(A4, t);
  t = cmul(w1, A7); float2 b6 = cadd(A6, t), b7 = csub(A6, t);
  t = cmul(w2, b2);                     float2 c0 = cadd(b0, t), c2 = csub(b0, t);
  t = cmul(w2, b3); t = INV ? mulpi(t) : mulni(t);
  float2 c1 = cadd(b1, t), c3 = csub(b1, t);
  t = cmul(w2, b6);                     float2 c4 = cadd(b4, t), c6 = csub(b4, t);
  t = cmul(w2, b7); t = INV ? mulpi(t) : mulni(t);
  float2 c5 = cadd(b5, t), c7 = csub(b5, t);
  t = cmul(w3, c4); A0 = cadd(c0, t); A4 = csub(c0, t);
  float2 e1 = cmul(w3, c5);
  t = INV ? make_float2(C8 * (e1.x - e1.y), C8 * (e1.y + e1.x))
          : make_float2(C8 * (e1.x + e1.y), C8 * (e1.y - e1.x));
  A1 = cadd(c1, t); A5 = csub(c1, t);
  float2 e2 = cmul(w3, c6); t = INV ? mulpi(e2) : mulni(e2);
  A2 = cadd(c2, t); A6 = csub(c2, t);
  float2 e3 = cmul(w3, c7);
  t = INV ? make_float2(-C8 * (e3.x + e3.y), C8 * (e3.x - e3.y))
          : make_float2(C8 * (e3.y - e3.x), -C8 * (e3.x + e3.y));
  A3 = cadd(c3, t); A7 = csub(c3, t);
}

// ---- passes 0..2 of the 4096-pt FFT: NO block barrier (exchanges are intra-wave)
template<bool INV>
__device__ __forceinline__ void fft4k_01(float2* Z, const float2* __restrict__ tw) {
  const int tid = threadIdx.x;
#pragma unroll
  for (int p = 0; p < 3; ++p) {
    const int hs = 3 * p;
    const int h = 1 << hs;
    const int j0 = tid & (h - 1);
    const int i = ((tid >> hs) << (hs + 3)) + j0;
    int s0 = SLT(i),         s1 = SLT(i + h),     s2 = SLT(i + 2 * h), s3 = SLT(i + 3 * h);
    int s4 = SLT(i + 4 * h), s5 = SLT(i + 5 * h), s6 = SLT(i + 6 * h), s7 = SLT(i + 7 * h);
    float2 a0 = Z[s0], a1 = Z[s1], a2 = Z[s2], a3 = Z[s3];
    float2 a4 = Z[s4], a5 = Z[s5], a6 = Z[s6], a7 = Z[s7];
    float2 w1 = tw[j0 << (12 - hs)];
    float2 w2 = tw[j0 << (11 - hs)];
    float2 w3 = tw[j0 << (10 - hs)];
    if (INV) { w1.y = -w1.y; w2.y = -w2.y; w3.y = -w3.y; }
    bfly8<INV>(a0, a1, a2, a3, a4, a5, a6, a7, w1, w2, w3);
    Z[s0] = a0; Z[s1] = a1; Z[s2] = a2; Z[s3] = a3;
    Z[s4] = a4; Z[s5] = a5; Z[s6] = a6; Z[s7] = a7;
    __builtin_amdgcn_wave_barrier();
  }
}

// ---- pass 3 (stride 512, cross-wave): caller must __syncthreads() before.
template<bool INV>
__device__ __forceinline__ void fft4k_p3(const float2* Z, const float2* __restrict__ tw,
                                         float2 d[8]) {
  const int t = threadIdx.x;
#pragma unroll
  for (int k = 0; k < 8; ++k) d[k] = Z[SLT(t + 512 * k)];
  float2 w1 = tw[t << 3], w2 = tw[t << 2], w3 = tw[t << 1];
  if (INV) { w1.y = -w1.y; w2.y = -w2.y; w3.y = -w3.y; }
  bfly8<INV>(d[0], d[1], d[2], d[3], d[4], d[5], d[6], d[7], w1, w2, w3);
}

// ---------- LN1 + 3-channel projection (blocks < NB*LL/4) ∪ SIREN FFN hidden (rest)
__global__ __launch_bounds__(256) void k_lnproj_ffn(
    const float* __restrict__ u, const float* __restrict__ n1w, const float* __restrict__ n1b,
    const float* __restrict__ pw, const float* __restrict__ pb,
    float* __restrict__ xp0, float* __restrict__ xp1, float* __restrict__ xpL,
    const float* __restrict__ pos_z,
    const float* __restrict__ w0, const float* __restrict__ b0, const float* __restrict__ f0,
    const float* __restrict__ w1, const float* __restrict__ b1, const float* __restrict__ f1,
    const float* __restrict__ w2, const float* __restrict__ b2, const float* __restrict__ f2,
    float* __restrict__ hid2T) {
  __shared__ float zin[4][66];
  __shared__ float hbuf[4][64];
  const int g = threadIdx.x >> 6, lane = threadIdx.x & 63;
  if (blockIdx.x < (NB * LL) / 4) {
    const int r = blockIdx.x * 4 + g;
    const float* ur = u + (size_t)r * DD;
    float4 uv[4];
    float s = 0.f, sq = 0.f;
#pragma unroll
    for (int c = 0; c < 4; ++c) {
      uv[c] = ((const float4*)ur)[lane + 64 * c];
      s += uv[c].x + uv[c].y + uv[c].z + uv[c].w;
      sq += uv[c].x * uv[c].x + uv[c].y * uv[c].y + uv[c].z * uv[c].z + uv[c].w * uv[c].w;
    }
    for (int m = 1; m < 64; m <<= 1) { s += __shfl_xor(s, m); sq += __shfl_xor(sq, m); }
    const float mean = s * (1.0f / DD);
    const float var = sq * (1.0f / DD) - mean * mean;
    const float rs = rsqrtf(var + 1e-5f);
    float d0 = 0.f, d1 = 0.f, dL = 0.f;
    const float* pwL = pw + (size_t)3071 * DD;
#pragma unroll
    for (int c = 0; c < 4; ++c) {
      int i4 = lane + 64 * c;
      float4 wv = ((const float4*)n1w)[i4];
      float4 bv = ((const float4*)n1b)[i4];
      float4 p0 = ((const float4*)pw)[i4];
      float4 p1v = ((const float4*)(pw + DD))[i4];
      float4 pLv = ((const float4*)pwL)[i4];
      float xn;
      xn = (uv[c].x - mean) * rs * wv.x + bv.x; d0 += xn * p0.x; d1 += xn * p1v.x; dL += xn * pLv.x;
      xn = (uv[c].y - mean) * rs * wv.y + bv.y; d0 += xn * p0.y; d1 += xn * p1v.y; dL += xn * pLv.y;
      xn = (uv[c].z - mean) * rs * wv.z + bv.z; d0 += xn * p0.z; d1 += xn * p1v.z; dL += xn * pLv.z;
      xn = (uv[c].w - mean) * rs * wv.w + bv.w; d0 += xn * p0.w; d1 += xn * p1v.w; dL += xn * pLv.w;
    }
    for (int m = 1; m < 64; m <<= 1) {
      d0 += __shfl_xor(d0, m); d1 += __shfl_xor(d1, m); dL += __shfl_xor(dL, m);
    }
    if (lane == 0) {
      xp0[r] = d0 + pb[0];
      xp1[r] = d1 + pb[1];
      xpL[r] = dL + pb[3071];
    }
  } else {
    const int l0 = (blockIdx.x - (NB * LL) / 4) * 16;
    for (int it = 0; it < 4; ++it) {
      const int l = l0 + g * 4 + it;
      zin[g][lane] = pos_z[(size_t)l * 65 + lane];
      if (lane == 0) zin[g][64] = pos_z[(size_t)l * 65 + 64];
      __syncthreads();
      float acc = b0[lane];
#pragma unroll
      for (int k = 0; k < 65; ++k) acc += zin[g][k] * w0[lane * 65 + k];
      float hv = sinf(f0[lane] * acc);
      __syncthreads();
      hbuf[g][lane] = hv;
      __syncthreads();
      acc = b1[lane];
#pragma unroll
      for (int k = 0; k < 64; ++k) acc += hbuf[g][k] * w1[lane * 64 + k];
      hv = sinf(f1[lane] * acc);
      __syncthreads();
      hbuf[g][lane] = hv;
      __syncthreads();
      acc = b2[lane];
#pragma unroll
      for (int k = 0; k < 64; ++k) acc += hbuf[g][k] * w2[lane * 64 + k];
      hv = sinf(f2[lane] * acc);
      hid2T[(size_t)lane * LL + l] = hv;
      __syncthreads();
    }
  }
}

// ------ 3-tap conv (blocks < 64) ∪ twiddles (64..79) ∪ fcw cast (80..1103)
__global__ __launch_bounds__(256) void k_tapconv_prep(
    const float* __restrict__ xp0, const float* __restrict__ xp1, const float* __restrict__ xpL,
    const float* __restrict__ cw, const float* __restrict__ cb,
    float* __restrict__ x0c, float* __restrict__ x1c, float* __restrict__ xLc,
    float2* tw, const float* __restrict__ fcw, unsigned short* __restrict__ fcwb) {
  const int bid = blockIdx.x;
  if (bid < 64) {
    int idx = bid * 256 + threadIdx.x;
    int l = idx & (LL - 1);
    int base = idx - l;
    {
      const float* a = xp0 + base;
      float v = cw[2] * a[l];
      if (l >= 1) v += cw[1] * a[l - 1];
      if (l >= 2) v += cw[0] * a[l - 2];
      x0c[idx] = v + cb[0];
    }
    {
      const float* a = xp1 + base;
      float v = cw[5] * a[l];
      if (l >= 1) v += cw[4] * a[l - 1];
      if (l >= 2) v += cw[3] * a[l - 2];
      x1c[idx] = v + cb[1];
    }
    {
      const float* a = xpL + base;
      float v = cw[3071 * 3 + 2] * a[l];
      if (l >= 1) v += cw[3071 * 3 + 1] * a[l - 1];
      if (l >= 2) v += cw[3071 * 3 + 0] * a[l - 2];
      xLc[idx] = v + cb[3071];
    }
  } else if (bid < 80) {
    int k = (bid - 64) * 256 + threadIdx.x;
    float ang = -2.0f * PI_F * (float)k / 8192.0f;
    float s, c;
    sincosf(ang, &s, &c);
    tw[k] = make_float2(c, s);
  } else {
    int i = (bid - 80) * 256 + threadIdx.x;   // i < 1024*1024/4
    float4 v = ((const float4*)fcw)[i];
    ushort4 o;
    o.x = f2bf(v.x); o.y = f2bf(v.y); o.z = f2bf(v.z); o.w = f2bf(v.w);
    ((ushort4*)fcwb)[i] = o;
  }
}

// ------- filter bank GEMM + decay: h[o][l] = (Σ_k hid2T[k][l] wout[o][k]) * exp(a_d t_l)
#define FG_CH 16
__global__ __launch_bounds__(256) void k_filter_gemm(
    const float* __restrict__ hid2T, const float* __restrict__ wout,
    const float* __restrict__ alphas, const float* __restrict__ pos_t,
    float* __restrict__ h) {
  __shared__ float wdl[FG_CH][64];
  const int cg = blockIdx.x & 127;
  const int lg = blockIdx.x >> 7;
  const int t = threadIdx.x;
  for (int idx = t; idx < FG_CH * 64; idx += 256) {
    int c = idx >> 6, k = idx & 63;
    wdl[c][k] = wout[(size_t)(cg * FG_CH + c) * 64 + k];
  }
  __syncthreads();
  const int l0 = lg * 1024 + 4 * t;
  float4 acc[FG_CH];
#pragma unroll
  for (int c = 0; c < FG_CH; ++c) acc[c] = make_float4(0.f, 0.f, 0.f, 0.f);
  for (int k = 0; k < 64; ++k) {
    float4 hv = *(const float4*)&hid2T[(size_t)k * LL + l0];
#pragma unroll
    for (int c = 0; c < FG_CH; ++c) {
      acc[c].x = fmaf(hv.x, wdl[c][k], acc[c].x);
      acc[c].y = fmaf(hv.y, wdl[c][k], acc[c].y);
      acc[c].z = fmaf(hv.z, wdl[c][k], acc[c].z);
      acc[c].w = fmaf(hv.w, wdl[c][k], acc[c].w);
    }
  }
  float4 tt = *(const float4*)&pos_t[l0];
#pragma unroll
  for (int c = 0; c < FG_CH; ++c) {
    int ch = cg * FG_CH + c;
    float a = alphas[ch & (DD - 1)];
    float4 o;
    o.x = acc[c].x * expf(a * tt.x);
    o.y = acc[c].y * expf(a * tt.y);
    o.z = acc[c].z * expf(a * tt.z);
    o.w = acc[c].w * expf(a * tt.w);
    *(float4*)&h[(size_t)ch * LL + l0] = o;
  }
}

// ----- spectra: filter rows h[bid] (blocks < 2048) ∪ v0 rows xLc (blocks 2048..2051)
__global__ __launch_bounds__(512, 4) void k_fft_filters(
    const float* __restrict__ h, const float* __restrict__ xLc,
    float2* __restrict__ Hs, float2* __restrict__ V0s, const float2* __restrict__ tw) {
  __shared__ float2 Z[NSLOT4];
  const int tid = threadIdx.x;
  const int bid = blockIdx.x;
  const float2* src = (bid < 2048) ? (const float2*)(h + (size_t)bid * LL)
                                   : (const float2*)(xLc + (size_t)(bid - 2048) * LL);
  float2* Out = (bid < 2048) ? (Hs + (size_t)bid * KBINS)
                             : (V0s + (size_t)(bid - 2048) * KBINS);
#pragma unroll
  for (int gi = 0; gi < 4; ++gi) {
    int j = tid + gi * 512;
    float2 v = src[j];
    int r = brev12(j);  // even; r+1 is the zero-pad partner
    Z[SLT(r)] = v;
    Z[SLT(r + 1)] = make_float2(0.f, 0.f);
  }
  __syncthreads();
  fft4k_01<false>(Z, tw);
  __syncthreads();
  float2 dd[8];
  fft4k_p3<false>(Z, tw, dd);
#pragma unroll
  for (int k = 0; k < 8; ++k) Z[SLT(tid + 512 * k)] = dd[k];  // own slots: race-free
  __syncthreads();
  // twist: X[k] = E + W_k*O;  X[4096-k] = conj(E - W_k*O)
#pragma unroll
  for (int gi = 0; gi < 4; ++gi) {
    int k = tid + gi * 512;
    float2 zk = Z[SLT(k)];
    float2 zm = Z[SLT((N4 - k) & (N4 - 1))];
    float2 B = conjf(zm);
    float2 E = make_float2(0.5f * (zk.x + B.x), 0.5f * (zk.y + B.y));
    float2 F = make_float2(0.5f * (zk.x - B.x), 0.5f * (zk.y - B.y));
    float2 G = cmul(tw[k], F);
    float2 WO = mulni(G);
    Out[k] = cadd(E, WO);
    Out[N4 - k] = conjf(csub(E, WO));
  }
  if (tid == 0) {
    float2 zc = Z[SLT(2048)];
    float2 F = make_float2(0.f, zc.y);
    float2 G = cmul(tw[2048], F);
    Out[2048] = cadd(make_float2(zc.x, 0.f), mulni(G));
  }
}

// ---------- fused conv1+conv2, one (b,d) channel per block, 9-barrier schedule
__global__ __launch_bounds__(512, 4) void k_conv12(
    const float2* __restrict__ Hs, const float2* __restrict__ V0s,
    const float* __restrict__ x0c, const float* __restrict__ x1c, const float* __restrict__ xLc,
    const float* __restrict__ hyb, float* __restrict__ v2, const float2* __restrict__ tw) {
  __shared__ float2 Z[NSLOT4];
  const int b = blockIdx.x >> 10, d = blockIdx.x & 1023;
  const int tid = threadIdx.x;
  const float2* H0 = Hs + (size_t)d * KBINS;
  const float2* H1 = Hs + (size_t)(DD + d) * KBINS;
  const float2* V = V0s + (size_t)b * KBINS;
  const float2* g0 = (const float2*)(x0c + (size_t)b * LL);
  const float2* g1 = (const float2*)(x1c + (size_t)b * LL);
  const float2* v0 = (const float2*)(xLc + (size_t)b * LL);
  // ---- ISSUE-EARLY: gate1 operand loads (used after FFT-A)
  float2 gg0[4], vv0[4];
#pragma unroll
  for (int k = 0; k < 4; ++k) {
    int j = tid + 512 * k;
    gg0[k] = g0[j];
    vv0[k] = v0[j];
  }
  // ---- product1 (Y = V*H0) + inverse twist + bit-rev scatter
#pragma unroll
  for (int gi = 0; gi < 4; ++gi) {
    int k = tid + gi * 512;  // 0..2047
    int m = N4 - k;          // 2049..4096
    float2 Yk = cmul(V[k], H0[k]);
    float2 Ym = cmul(V[m], H0[m]);
    float2 B = conjf(Ym);
    float2 E = make_float2(0.5f * (Yk.x + B.x), 0.5f * (Yk.y + B.y));
    float2 F = make_float2(0.5f * (Yk.x - B.x), 0.5f * (Yk.y - B.y));
    float2 O = cmul(conjf(tw[k]), F);
    float2 iO = mulpi(O);
    Z[SLT(brev12(k))] = cadd(E, iO);
    if (k > 0) Z[SLT(brev12(m))] = conjf(csub(E, iO));
  }
  if (tid == 0) {
    float2 A = cmul(V[2048], H0[2048]);
    float2 F = make_float2(0.f, A.y);
    float2 O = cmul(conjf(tw[2048]), F);
    Z[SLT(brev12(2048))] = cadd(make_float2(A.x, 0.f), mulpi(O));
  }
  __syncthreads();                       // b1
  fft4k_01<true>(Z, tw);
  __syncthreads();                       // b2
  float2 dA[8];
  fft4k_p3<true>(Z, tw, dA);             // time samples z[tid+512k] in regs
  // ---- gate1 in regs (only k<4: first 4096 reals of v1)
  const float bd0 = hyb[d], bd1 = hyb[DD + d];
  float2 vsave[4];
#pragma unroll
  for (int k = 0; k < 4; ++k) {
    vsave[k] = make_float2(gg0[k].x * fmaf(dA[k].x, INV4, bd0 * vv0[k].x),
                           gg0[k].y * fmaf(dA[k].y, INV4, bd0 * vv0[k].y));
  }
  __syncthreads();                       // b3 (all p3 reads complete)
#pragma unroll
  for (int k = 0; k < 4; ++k) {
    int j = tid + 512 * k;
    int r = brev12(j);                   // even
    Z[SLT(r)] = vsave[k];
    Z[SLT(r + 1)] = make_float2(0.f, 0.f);
  }
  __syncthreads();                       // b4
  fft4k_01<false>(Z, tw);
  __syncthreads();                       // b5
  float2 dB[8];
  fft4k_p3<false>(Z, tw, dB);
#pragma unroll
  for (int k = 0; k < 8; ++k) Z[SLT(tid + 512 * k)] = dB[k];  // own slots: race-free
  __syncthreads();                       // b6
  // ---- ISSUE-EARLY: gate2 operand loads (used after FFT-C)
  float2 gg1[4];
#pragma unroll
  for (int k = 0; k < 4; ++k) gg1[k] = g1[tid + 512 * k];
  // ---- fwd twist + product2 (Y = X*H1) + inverse twist, in regs
  float2 zpk[4], zpm[4], z2048;
#pragma unroll
  for (int gi = 0; gi < 4; ++gi) {
    int k = tid + gi * 512;
    int m = N4 - k;
    float2 zk = Z[SLT(k)];
    float2 zm = Z[SLT(m & (N4 - 1))];
    float2 B = conjf(zm);
    float2 E = make_float2(0.5f * (zk.x + B.x), 0.5f * (zk.y + B.y));
    float2 F = make_float2(0.5f * (zk.x - B.x), 0.5f * (zk.y - B.y));
    float2 wk = tw[k];
    float2 G = cmul(wk, F);
    float2 WO = mulni(G);
    float2 Xk = cadd(E, WO);
    float2 Xm = conjf(csub(E, WO));
    float2 Yk = cmul(Xk, H1[k]);
    float2 Ym = cmul(Xm, H1[m]);
    float2 B2 = conjf(Ym);
    float2 E2 = make_float2(0.5f * (Yk.x + B2.x), 0.5f * (Yk.y + B2.y));
    float2 F2 = make_float2(0.5f * (Yk.x - B2.x), 0.5f * (Yk.y - B2.y));
    float2 O2 = cmul(conjf(wk), F2);
    float2 iO2 = mulpi(O2);
    zpk[gi] = cadd(E2, iO2);
    zpm[gi] = conjf(csub(E2, iO2));
  }
  if (tid == 0) {
    float2 zc = Z[SLT(2048)];
    float2 F = make_float2(0.f, zc.y);
    float2 G = cmul(tw[2048], F);
    float2 Xk = cadd(make_float2(zc.x, 0.f), mulni(G));
    float2 Y = cmul(Xk, H1[2048]);
    float2 F2 = make_float2(0.f, Y.y);
    float2 O2 = cmul(conjf(tw[2048]), F2);
    z2048 = cadd(make_float2(Y.x, 0.f), mulpi(O2));
  }
  __syncthreads();                       // b7 (reads done before scatter)
#pragma unroll
  for (int gi = 0; gi < 4; ++gi) {
    int k = tid + gi * 512;
    Z[SLT(brev12(k))] = zpk[gi];
    if (k > 0) Z[SLT(brev12(N4 - k))] = zpm[gi];
  }
  if (tid == 0) Z[SLT(brev12(2048))] = z2048;
  __syncthreads();                       // b8
  fft4k_01<true>(Z, tw);
  __syncthreads();                       // b9
  float2 dC[8];
  fft4k_p3<true>(Z, tw, dC);
  // ---- gate2 + store v2 (only k<4 needed)
  float2* out2 = (float2*)(v2 + ((size_t)b * DD + d) * LL);
#pragma unroll
  for (int k = 0; k < 4; ++k) {
    int j = tid + 512 * k;
    out2[j] = make_float2(gg1[k].x * fmaf(dC[k].x, INV4, bd1 * vsave[k].x),
                          gg1[k].y * fmaf(dC[k].y, INV4, bd1 * vsave[k].y));
  }
}

// ------------- fused transpose + residual + LN2:  y = u + v2^T (-> d_out);
// yln = LN2(y) as bf16.  Block = 16 l-rows x 1024 d, 512 threads, 65.8 KB LDS.
#define TL 16
__global__ __launch_bounds__(512) void k_transpose_ln2(
    const float* __restrict__ v2, const float* __restrict__ u,
    const float* __restrict__ w, const float* __restrict__ bb,
    float* __restrict__ y, unsigned short* __restrict__ yln) {
  __shared__ float T[TL][1028];  // row stride 1028 floats: 16B-aligned float4 rows
  const int b = blockIdx.x >> 8;          // 256 l-blocks per batch
  const int lb = (blockIdx.x & 255) * TL;
  const int t = threadIdx.x;
  // load: transpose v2[b][d][lb..lb+16) -> T[l][d]; lanes write consecutive d (no conflict)
#pragma unroll
  for (int dd = 0; dd < 2; ++dd) {
    const int d = t + dd * 512;
    const float4* src = (const float4*)(v2 + ((size_t)b * DD + d) * LL + lb);
#pragma unroll
    for (int q = 0; q < 4; ++q) {
      float4 v = src[q];
      T[4 * q + 0][d] = v.x;
      T[4 * q + 1][d] = v.y;
      T[4 * q + 2][d] = v.z;
      T[4 * q + 3][d] = v.w;
    }
  }
  __syncthreads();
  const int wv = t >> 6, lane = t & 63;   // 8 waves x 2 rows each
#pragma unroll
  for (int rr = 0; rr < 2; ++rr) {
    const int row = wv * 2 + rr;
    const int l = lb + row;
    const float* urow = u + ((size_t)b * LL + l) * DD;
    float4 v[4];
    float s = 0.f, sq = 0.f;
#pragma unroll
    for (int c = 0; c < 4; ++c) {
      int i4 = lane + 64 * c;
      float4 tv = *(const float4*)&T[row][4 * i4];
      float4 uv = ((const float4*)urow)[i4];
      tv.x += uv.x; tv.y += uv.y; tv.z += uv.z; tv.w += uv.w;
      v[c] = tv;
      s += tv.x + tv.y + tv.z + tv.w;
      sq += tv.x * tv.x + tv.y * tv.y + tv.z * tv.z + tv.w * tv.w;
    }
    for (int m = 1; m < 64; m <<= 1) { s += __shfl_xor(s, m); sq += __shfl_xor(sq, m); }
    const float mean = s * (1.0f / DD);
    const float var = sq * (1.0f / DD) - mean * mean;
    const float rs = rsqrtf(var + 1e-5f);
    float* yrow = y + ((size_t)b * LL + l) * DD;
    unsigned short* ybr = yln + ((size_t)b * LL + l) * DD;
#pragma unroll
    for (int c = 0; c < 4; ++c) {
      int i4 = lane + 64 * c;
      float4 wv4 = ((const float4*)w)[i4];
      float4 bv = ((const float4*)bb)[i4];
      ((float4*)yrow)[i4] = v[c];
      ushort4 o;
      o.x = f2bf((v[c].x - mean) * rs * wv4.x + bv.x);
      o.y = f2bf((v[c].y - mean) * rs * wv4.y + bv.y);
      o.z = f2bf((v[c].z - mean) * rs * wv4.z + bv.z);
      o.w = f2bf((v[c].w - mean) * rs * wv4.w + bv.w);
      ((ushort4*)ybr)[i4] = o;
    }
  }
}

// --------------- final GEMM: out = yln @ fcw^T + fcb + out  (out pre-seeded with y)
#define GBM 128
#define GBN 128
#define GBK 64
#if USE_GLOAD_LDS
#define LDK 64   // linear LDS: required by global_load_lds (wave-uniform base + lane*16)
#else
#define LDK 72   // padded reg-staging fallback
#endif

__global__ __launch_bounds__(256) void k_gemm(const short* __restrict__ A,
                                              const short* __restrict__ Bw,
                                              const float* __restrict__ fcb,
                                              float* out) {
  __shared__ short As[GBM * LDK];
  __shared__ short Bs[GBN * LDK];
  const int t = threadIdx.x;
  const int bm = blockIdx.x & 127;
  const int bn = blockIdx.x >> 7;
  const int wave = t >> 6, lane = t & 63;
  const int wr = wave >> 1, wc = wave & 1;
  const int rrow = lane & 15, kb = (lane >> 4) * 8;

  f32x4 acc[4][4];
#pragma unroll
  for (int i = 0; i < 4; ++i)
#pragma unroll
    for (int j = 0; j < 4; ++j) acc[i][j] = (f32x4){0.f, 0.f, 0.f, 0.f};

  const size_t abase = (size_t)(bm * GBM) * 1024;
  const size_t bbase = (size_t)(bn * GBN) * 1024;

  for (int k0 = 0; k0 < 1024; k0 += GBK) {
#if USE_GLOAD_LDS
    {
      const int r0 = wave * 32;
      const int lrow = lane >> 3, loff = (lane & 7) * 8;
#pragma unroll
      for (int q = 0; q < 4; ++q) {
        const int row = r0 + 8 * q + lrow;
        __builtin_amdgcn_global_load_lds(
            (const __attribute__((address_space(1))) void*)(A + abase + (size_t)row * 1024 + k0 + loff),
            (__attribute__((address_space(3))) void*)&As[(r0 + 8 * q) * LDK], 16, 0, 0);
        __builtin_amdgcn_global_load_lds(
            (const __attribute__((address_space(1))) void*)(Bw + bbase + (size_t)row * 1024 + k0 + loff),
            (__attribute__((address_space(3))) void*)&Bs[(r0 + 8 * q) * LDK], 16, 0, 0);
      }
    }
#else
#pragma unroll
    for (int c = 0; c < 4; ++c) {
      int chunk = c * 256 + t;
      int row = chunk >> 3, off = (chunk & 7) * 8;
      s16x8 av = *(const s16x8*)(A + abase + (size_t)row * 1024 + k0 + off);
      *(s16x8*)&As[row * LDK + off] = av;
      s16x8 bv = *(const s16x8*)(Bw + bbase + (size_t)row * 1024 + k0 + off);
      *(s16x8*)&Bs[row * LDK + off] = bv;
    }
#endif
    __syncthreads();
    s16x8 af[2][4], bfr[2][4];
#pragma unroll
    for (int ks = 0; ks < 2; ++ks) {
#pragma unroll
      for (int mr = 0; mr < 4; ++mr)
        af[ks][mr] = *(const s16x8*)&As[(wr * 64 + mr * 16 + rrow) * LDK + ks * 32 + kb];
#pragma unroll
      for (int nc = 0; nc < 4; ++nc)
        bfr[ks][nc] = *(const s16x8*)&Bs[(wc * 64 + nc * 16 + rrow) * LDK + ks * 32 + kb];
    }
#pragma unroll
    for (int ks = 0; ks < 2; ++ks)
#pragma unroll
      for (int mr = 0; mr < 4; ++mr)
#pragma unroll
        for (int nc = 0; nc < 4; ++nc)
          acc[mr][nc] = __builtin_amdgcn_mfma_f32_16x16x32_bf16(af[ks][mr], bfr[ks][nc],
                                                                acc[mr][nc], 0, 0, 0);
    __syncthreads();
  }
  const int cg = lane >> 4, cr = lane & 15;
#pragma unroll
  for (int mr = 0; mr < 4; ++mr)
#pragma unroll
    for (int nc = 0; nc < 4; ++nc) {
      f32x4 a = acc[mr][nc];
      int col = bn * GBN + wc * 64 + nc * 16 + cr;
#pragma unroll
      for (int q = 0; q < 4; ++q) {
        int row = bm * GBM + wr * 64 + mr * 16 + cg * 4 + q;
        size_t idx = (size_t)row * 1024 + col;
        out[idx] = a[q] + fcb[col] + out[idx];   // out pre-seeded with y
      }
    }
}

// ============================================================== launcher
extern "C" void kernel_launch(void* const* d_in, const int* in_sizes, int n_in,
                              void* d_out, int out_size, void* d_ws, size_t ws_size,
                              hipStream_t stream) {
  const float* u      = (const float*)d_in[0];
  const float* n1w    = (const float*)d_in[1];
  const float* n1b    = (const float*)d_in[2];
  const float* projw  = (const float*)d_in[3];
  const float* projb  = (const float*)d_in[4];
  const float* convw  = (const float*)d_in[5];
  const float* convb  = (const float*)d_in[6];
  const float* pos_t  = (const float*)d_in[7];
  const float* pos_z  = (const float*)d_in[8];
  const float* w0     = (const float*)d_in[9];
  const float* b0     = (const float*)d_in[10];
  const float* f0     = (const float*)d_in[11];
  const float* w1     = (const float*)d_in[12];
  const float* b1     = (const float*)d_in[13];
  const float* f1     = (const float*)d_in[14];
  const float* w2     = (const float*)d_in[15];
  const float* b2     = (const float*)d_in[16];
  const float* f2     = (const float*)d_in[17];
  const float* wout   = (const float*)d_in[18];
  const float* alphas = (const float*)d_in[19];
  const float* hyb    = (const float*)d_in[20];
  const float* n2w    = (const float*)d_in[21];
  const float* n2b    = (const float*)d_in[22];
  const float* fcw    = (const float*)d_in[23];
  const float* fcb    = (const float*)d_in[24];

  char* wsb = (char*)d_ws;
  size_t off = 0;
  auto alloc = [&](size_t bytes) -> void* {
    off = (off + 255) & ~(size_t)255;
    void* p = wsb + off;
    off += bytes;
    return p;
  };
  float2* tw    = (float2*)alloc(sizeof(float2) * 4096);
  float*  xp0   = (float*)alloc(sizeof(float) * NB * LL);
  float*  xp1   = (float*)alloc(sizeof(float) * NB * LL);
  float*  xpL   = (float*)alloc(sizeof(float) * NB * LL);
  float*  x0c   = (float*)alloc(sizeof(float) * NB * LL);
  float*  x1c   = (float*)alloc(sizeof(float) * NB * LL);
  float*  xLc   = (float*)alloc(sizeof(float) * NB * LL);
  float*  hid2T = (float*)alloc(sizeof(float) * 64 * LL);
  float2* Hs    = (float2*)alloc(sizeof(float2) * 2 * DD * KBINS);   // 67.1 MB
  float2* V0s   = (float2*)alloc(sizeof(float2) * NB * KBINS);
  float*  v2    = (float*)alloc(sizeof(float) * NB * DD * LL);       // 64 MB
  unsigned short* fcwb = (unsigned short*)alloc(sizeof(unsigned short) * DD * DD);
  float*          y   = (float*)d_out;        // y lives in the output buffer (64 MB)
  unsigned short* yln = (unsigned short*)Hs;  // overlay: Hs dead after k_conv12
  float*          h   = v2;                   // overlay: filter bank dead before conv12
  (void)ws_size; (void)in_sizes; (void)n_in; (void)out_size;

  k_lnproj_ffn<<<(NB * LL) / 4 + LL / 16, 256, 0, stream>>>(
      u, n1w, n1b, projw, projb, xp0, xp1, xpL,
      pos_z, w0, b0, f0, w1, b1, f1, w2, b2, f2, hid2T);
  k_tapconv_prep<<<64 + 16 + (DD * DD / 4) / 256, 256, 0, stream>>>(
      xp0, xp1, xpL, convw, convb, x0c, x1c, xLc, tw, fcw, fcwb);
  k_filter_gemm<<<512, 256, 0, stream>>>(hid2T, wout, alphas, pos_t, h);
  k_fft_filters<<<2048 + NB, 512, 0, stream>>>(h, xLc, Hs, V0s, tw);
  k_conv12<<<NB * DD, 512, 0, stream>>>(Hs, V0s, x0c, x1c, xLc, hyb, v2, tw);
  k_transpose_ln2<<<NB * (LL / TL), 512, 0, stream>>>(v2, u, n2w, n2b, y, yln);
  k_gemm<<<(16384 / GBM) * (1024 / GBN), 256, 0, stream>>>((const short*)yln, (const short*)fcwb,
                                                           fcb, (float*)d_out);
}

// Round 17
// 360.031 us; speedup vs baseline: 1.0242x; 1.0242x over previous
//
#include <hip/hip_runtime.h>
#include <hip/hip_bf16.h>

#define LL 4096
#define DD 1024
#define NB 4
#define N4 4096          // complex FFT size (packs 8192 reals)
#define KBINS 4097       // real-spectrum bins of the 8192-pt transform
#define NSLOT4 4366      // SLT(4095)+1
#define PI_F 3.14159265358979323846f
#define INV4 (1.0f / 4096.0f)

typedef __attribute__((ext_vector_type(4))) float f32x4;
typedef __attribute__((ext_vector_type(8))) short s16x8;

#if defined(__has_builtin)
#if __has_builtin(__builtin_amdgcn_global_load_lds)
#define USE_GLOAD_LDS 1
#endif
#endif
#ifndef USE_GLOAD_LDS
#define USE_GLOAD_LDS 0
#endif

__device__ __forceinline__ unsigned short f2bf(float f) {
  unsigned int x = __float_as_uint(f);
  x += 0x7fffu + ((x >> 16) & 1u);
  return (unsigned short)(x >> 16);
}

// padded LDS slot: 64-stride (bit-rev scatter) lands ~2-way, radix strides spread
__device__ __forceinline__ int SLT(int n) { return n + (n >> 4) + (n >> 8); }
__device__ __forceinline__ int brev12(int n) { return (int)(__brev((unsigned)n) >> 20); }

__device__ __forceinline__ float2 cmul(float2 a, float2 b) {
  return make_float2(a.x * b.x - a.y * b.y, a.x * b.y + a.y * b.x);
}
__device__ __forceinline__ float2 cadd(float2 a, float2 b) { return make_float2(a.x + b.x, a.y + b.y); }
__device__ __forceinline__ float2 csub(float2 a, float2 b) { return make_float2(a.x - b.x, a.y - b.y); }
__device__ __forceinline__ float2 conjf(float2 a) { return make_float2(a.x, -a.y); }
__device__ __forceinline__ float2 mulni(float2 v) { return make_float2(v.y, -v.x); }   // * -i
__device__ __forceinline__ float2 mulpi(float2 v) { return make_float2(-v.y, v.x); }   // * +i

// ------------------------------------------------ radix-8 butterfly (verified r5-r15)
template<bool INV>
__device__ __forceinline__ void bfly8(float2& A0, float2& A1, float2& A2, float2& A3,
                                      float2& A4, float2& A5, float2& A6, float2& A7,
                                      float2 w1, float2 w2, float2 w3) {
  const float C8 = 0.70710678118654752f;
  float2 t;
  t = cmul(w1, A1); float2 b0 = cadd(A0, t), b1 = csub(A0, t);
  t = cmul(w1, A3); float2 b2 = cadd(A2, t), b3 = csub(A2, t);
  t = cmul(w1, A5); float2 b4 = cadd(A4, t), b5 = csub(A4, t);
  t = cmul(w1, A7); float2 b6 = cadd(A6, t), b7 = csub(A6, t);
  t = cmul(w2, b2);                     float2 c0 = cadd(b0, t), c2 = csub(b0, t);
  t = cmul(w2, b3); t = INV ? mulpi(t) : mulni(t);
  float2 c1 = cadd(b1, t), c3 = csub(b1, t);
  t = cmul(w2, b6);                     float2 c4 = cadd(b4, t), c6 = csub(b4, t);
  t = cmul(w2, b7); t = INV ? mulpi(t) : mulni(t);
  float2 c5 = cadd(b5, t), c7 = csub(b5, t);
  t = cmul(w3, c4); A0 = cadd(c0, t); A4 = csub(c0, t);
  float2 e1 = cmul(w3, c5);
  t = INV ? make_float2(C8 * (e1.x - e1.y), C8 * (e1.y + e1.x))
          : make_float2(C8 * (e1.x + e1.y), C8 * (e1.y - e1.x));
  A1 = cadd(c1, t); A5 = csub(c1, t);
  float2 e2 = cmul(w3, c6); t = INV ? mulpi(e2) : mulni(e2);
  A2 = cadd(c2, t); A6 = csub(c2, t);
  float2 e3 = cmul(w3, c7);
  t = INV ? make_float2(-C8 * (e3.x + e3.y), C8 * (e3.x - e3.y))
          : make_float2(C8 * (e3.y - e3.x), -C8 * (e3.x + e3.y));
  A3 = cadd(c3, t); A7 = csub(c3, t);
}

// ---- passes 0..2 of the 4096-pt FFT: NO block barrier (exchanges are intra-wave)
template<bool INV>
__device__ __forceinline__ void fft4k_01(float2* Z, const float2* __restrict__ tw) {
  const int tid = threadIdx.x;
#pragma unroll
  for (int p = 0; p < 3; ++p) {
    const int hs = 3 * p;
    const int h = 1 << hs;
    const int j0 = tid & (h - 1);
    const int i = ((tid >> hs) << (hs + 3)) + j0;
    int s0 = SLT(i),         s1 = SLT(i + h),     s2 = SLT(i + 2 * h), s3 = SLT(i + 3 * h);
    int s4 = SLT(i + 4 * h), s5 = SLT(i + 5 * h), s6 = SLT(i + 6 * h), s7 = SLT(i + 7 * h);
    float2 a0 = Z[s0], a1 = Z[s1], a2 = Z[s2], a3 = Z[s3];
    float2 a4 = Z[s4], a5 = Z[s5], a6 = Z[s6], a7 = Z[s7];
    float2 w1 = tw[j0 << (12 - hs)];
    float2 w2 = tw[j0 << (11 - hs)];
    float2 w3 = tw[j0 << (10 - hs)];
    if (INV) { w1.y = -w1.y; w2.y = -w2.y; w3.y = -w3.y; }
    bfly8<INV>(a0, a1, a2, a3, a4, a5, a6, a7, w1, w2, w3);
    Z[s0] = a0; Z[s1] = a1; Z[s2] = a2; Z[s3] = a3;
    Z[s4] = a4; Z[s5] = a5; Z[s6] = a6; Z[s7] = a7;
    __builtin_amdgcn_wave_barrier();
  }
}

// ---- pass 3 (stride 512, cross-wave): caller must __syncthreads() before.
template<bool INV>
__device__ __forceinline__ void fft4k_p3(const float2* Z, const float2* __restrict__ tw,
                                         float2 d[8]) {
  const int t = threadIdx.x;
#pragma unroll
  for (int k = 0; k < 8; ++k) d[k] = Z[SLT(t + 512 * k)];
  float2 w1 = tw[t << 3], w2 = tw[t << 2], w3 = tw[t << 1];
  if (INV) { w1.y = -w1.y; w2.y = -w2.y; w3.y = -w3.y; }
  bfly8<INV>(d[0], d[1], d[2], d[3], d[4], d[5], d[6], d[7], w1, w2, w3);
}

// ---------- LN1 + 3-channel projection (blocks < NB*LL/4) ∪ SIREN FFN hidden (rest)
__global__ __launch_bounds__(256) void k_lnproj_ffn(
    const float* __restrict__ u, const float* __restrict__ n1w, const float* __restrict__ n1b,
    const float* __restrict__ pw, const float* __restrict__ pb,
    float* __restrict__ xp0, float* __restrict__ xp1, float* __restrict__ xpL,
    const float* __restrict__ pos_z,
    const float* __restrict__ w0, const float* __restrict__ b0, const float* __restrict__ f0,
    const float* __restrict__ w1, const float* __restrict__ b1, const float* __restrict__ f1,
    const float* __restrict__ w2, const float* __restrict__ b2, const float* __restrict__ f2,
    float* __restrict__ hid2T) {
  __shared__ float zin[4][66];
  __shared__ float hbuf[4][64];
  const int g = threadIdx.x >> 6, lane = threadIdx.x & 63;
  if (blockIdx.x < (NB * LL) / 4) {
    const int r = blockIdx.x * 4 + g;
    const float* ur = u + (size_t)r * DD;
    float4 uv[4];
    float s = 0.f, sq = 0.f;
#pragma unroll
    for (int c = 0; c < 4; ++c) {
      uv[c] = ((const float4*)ur)[lane + 64 * c];
      s += uv[c].x + uv[c].y + uv[c].z + uv[c].w;
      sq += uv[c].x * uv[c].x + uv[c].y * uv[c].y + uv[c].z * uv[c].z + uv[c].w * uv[c].w;
    }
    for (int m = 1; m < 64; m <<= 1) { s += __shfl_xor(s, m); sq += __shfl_xor(sq, m); }
    const float mean = s * (1.0f / DD);
    const float var = sq * (1.0f / DD) - mean * mean;
    const float rs = rsqrtf(var + 1e-5f);
    float d0 = 0.f, d1 = 0.f, dL = 0.f;
    const float* pwL = pw + (size_t)3071 * DD;
#pragma unroll
    for (int c = 0; c < 4; ++c) {
      int i4 = lane + 64 * c;
      float4 wv = ((const float4*)n1w)[i4];
      float4 bv = ((const float4*)n1b)[i4];
      float4 p0 = ((const float4*)pw)[i4];
      float4 p1v = ((const float4*)(pw + DD))[i4];
      float4 pLv = ((const float4*)pwL)[i4];
      float xn;
      xn = (uv[c].x - mean) * rs * wv.x + bv.x; d0 += xn * p0.x; d1 += xn * p1v.x; dL += xn * pLv.x;
      xn = (uv[c].y - mean) * rs * wv.y + bv.y; d0 += xn * p0.y; d1 += xn * p1v.y; dL += xn * pLv.y;
      xn = (uv[c].z - mean) * rs * wv.z + bv.z; d0 += xn * p0.z; d1 += xn * p1v.z; dL += xn * pLv.z;
      xn = (uv[c].w - mean) * rs * wv.w + bv.w; d0 += xn * p0.w; d1 += xn * p1v.w; dL += xn * pLv.w;
    }
    for (int m = 1; m < 64; m <<= 1) {
      d0 += __shfl_xor(d0, m); d1 += __shfl_xor(d1, m); dL += __shfl_xor(dL, m);
    }
    if (lane == 0) {
      xp0[r] = d0 + pb[0];
      xp1[r] = d1 + pb[1];
      xpL[r] = dL + pb[3071];
    }
  } else {
    const int l0 = (blockIdx.x - (NB * LL) / 4) * 16;
    for (int it = 0; it < 4; ++it) {
      const int l = l0 + g * 4 + it;
      zin[g][lane] = pos_z[(size_t)l * 65 + lane];
      if (lane == 0) zin[g][64] = pos_z[(size_t)l * 65 + 64];
      __syncthreads();
      float acc = b0[lane];
#pragma unroll
      for (int k = 0; k < 65; ++k) acc += zin[g][k] * w0[lane * 65 + k];
      float hv = sinf(f0[lane] * acc);
      __syncthreads();
      hbuf[g][lane] = hv;
      __syncthreads();
      acc = b1[lane];
#pragma unroll
      for (int k = 0; k < 64; ++k) acc += hbuf[g][k] * w1[lane * 64 + k];
      hv = sinf(f1[lane] * acc);
      __syncthreads();
      hbuf[g][lane] = hv;
      __syncthreads();
      acc = b2[lane];
#pragma unroll
      for (int k = 0; k < 64; ++k) acc += hbuf[g][k] * w2[lane * 64 + k];
      hv = sinf(f2[lane] * acc);
      hid2T[(size_t)lane * LL + l] = hv;
      __syncthreads();
    }
  }
}

// ------ 3-tap conv (blocks < 64) ∪ twiddles (64..79) ∪ fcw cast (80..1103)
__global__ __launch_bounds__(256) void k_tapconv_prep(
    const float* __restrict__ xp0, const float* __restrict__ xp1, const float* __restrict__ xpL,
    const float* __restrict__ cw, const float* __restrict__ cb,
    float* __restrict__ x0c, float* __restrict__ x1c, float* __restrict__ xLc,
    float2* tw, const float* __restrict__ fcw, unsigned short* __restrict__ fcwb) {
  const int bid = blockIdx.x;
  if (bid < 64) {
    int idx = bid * 256 + threadIdx.x;
    int l = idx & (LL - 1);
    int base = idx - l;
    {
      const float* a = xp0 + base;
      float v = cw[2] * a[l];
      if (l >= 1) v += cw[1] * a[l - 1];
      if (l >= 2) v += cw[0] * a[l - 2];
      x0c[idx] = v + cb[0];
    }
    {
      const float* a = xp1 + base;
      float v = cw[5] * a[l];
      if (l >= 1) v += cw[4] * a[l - 1];
      if (l >= 2) v += cw[3] * a[l - 2];
      x1c[idx] = v + cb[1];
    }
    {
      const float* a = xpL + base;
      float v = cw[3071 * 3 + 2] * a[l];
      if (l >= 1) v += cw[3071 * 3 + 1] * a[l - 1];
      if (l >= 2) v += cw[3071 * 3 + 0] * a[l - 2];
      xLc[idx] = v + cb[3071];
    }
  } else if (bid < 80) {
    int k = (bid - 64) * 256 + threadIdx.x;
    float ang = -2.0f * PI_F * (float)k / 8192.0f;
    float s, c;
    sincosf(ang, &s, &c);
    tw[k] = make_float2(c, s);
  } else {
    int i = (bid - 80) * 256 + threadIdx.x;   // i < 1024*1024/4
    float4 v = ((const float4*)fcw)[i];
    ushort4 o;
    o.x = f2bf(v.x); o.y = f2bf(v.y); o.z = f2bf(v.z); o.w = f2bf(v.w);
    ((ushort4*)fcwb)[i] = o;
  }
}

// ------- filter bank GEMM + decay: h[o][l] = (Σ_k hid2T[k][l] wout[o][k]) * exp(a_d t_l)
#define FG_CH 16
__global__ __launch_bounds__(256) void k_filter_gemm(
    const float* __restrict__ hid2T, const float* __restrict__ wout,
    const float* __restrict__ alphas, const float* __restrict__ pos_t,
    float* __restrict__ h) {
  __shared__ float wdl[FG_CH][64];
  const int cg = blockIdx.x & 127;
  const int lg = blockIdx.x >> 7;
  const int t = threadIdx.x;
  for (int idx = t; idx < FG_CH * 64; idx += 256) {
    int c = idx >> 6, k = idx & 63;
    wdl[c][k] = wout[(size_t)(cg * FG_CH + c) * 64 + k];
  }
  __syncthreads();
  const int l0 = lg * 1024 + 4 * t;
  float4 acc[FG_CH];
#pragma unroll
  for (int c = 0; c < FG_CH; ++c) acc[c] = make_float4(0.f, 0.f, 0.f, 0.f);
  for (int k = 0; k < 64; ++k) {
    float4 hv = *(const float4*)&hid2T[(size_t)k * LL + l0];
#pragma unroll
    for (int c = 0; c < FG_CH; ++c) {
      acc[c].x = fmaf(hv.x, wdl[c][k], acc[c].x);
      acc[c].y = fmaf(hv.y, wdl[c][k], acc[c].y);
      acc[c].z = fmaf(hv.z, wdl[c][k], acc[c].z);
      acc[c].w = fmaf(hv.w, wdl[c][k], acc[c].w);
    }
  }
  float4 tt = *(const float4*)&pos_t[l0];
#pragma unroll
  for (int c = 0; c < FG_CH; ++c) {
    int ch = cg * FG_CH + c;
    float a = alphas[ch & (DD - 1)];
    float4 o;
    o.x = acc[c].x * expf(a * tt.x);
    o.y = acc[c].y * expf(a * tt.y);
    o.z = acc[c].z * expf(a * tt.z);
    o.w = acc[c].w * expf(a * tt.w);
    *(float4*)&h[(size_t)ch * LL + l0] = o;
  }
}

// ----- spectra: filter rows h[bid] (blocks < 2048) ∪ v0 rows xLc (blocks 2048..2051)
__global__ __launch_bounds__(512, 4) void k_fft_filters(
    const float* __restrict__ h, const float* __restrict__ xLc,
    float2* __restrict__ Hs, float2* __restrict__ V0s, const float2* __restrict__ tw) {
  __shared__ float2 Z[NSLOT4];
  const int tid = threadIdx.x;
  const int bid = blockIdx.x;
  const float2* src = (bid < 2048) ? (const float2*)(h + (size_t)bid * LL)
                                   : (const float2*)(xLc + (size_t)(bid - 2048) * LL);
  float2* Out = (bid < 2048) ? (Hs + (size_t)bid * KBINS)
                             : (V0s + (size_t)(bid - 2048) * KBINS);
#pragma unroll
  for (int gi = 0; gi < 4; ++gi) {
    int j = tid + gi * 512;
    float2 v = src[j];
    int r = brev12(j);  // even; r+1 is the zero-pad partner
    Z[SLT(r)] = v;
    Z[SLT(r + 1)] = make_float2(0.f, 0.f);
  }
  __syncthreads();
  fft4k_01<false>(Z, tw);
  __syncthreads();
  float2 dd[8];
  fft4k_p3<false>(Z, tw, dd);
#pragma unroll
  for (int k = 0; k < 8; ++k) Z[SLT(tid + 512 * k)] = dd[k];  // own slots: race-free
  __syncthreads();
  // twist: X[k] = E + W_k*O;  X[4096-k] = conj(E - W_k*O)
#pragma unroll
  for (int gi = 0; gi < 4; ++gi) {
    int k = tid + gi * 512;
    float2 zk = Z[SLT(k)];
    float2 zm = Z[SLT((N4 - k) & (N4 - 1))];
    float2 B = conjf(zm);
    float2 E = make_float2(0.5f * (zk.x + B.x), 0.5f * (zk.y + B.y));
    float2 F = make_float2(0.5f * (zk.x - B.x), 0.5f * (zk.y - B.y));
    float2 G = cmul(tw[k], F);
    float2 WO = mulni(G);
    Out[k] = cadd(E, WO);
    Out[N4 - k] = conjf(csub(E, WO));
  }
  if (tid == 0) {
    float2 zc = Z[SLT(2048)];
    float2 F = make_float2(0.f, zc.y);
    float2 G = cmul(tw[2048], F);
    Out[2048] = cadd(make_float2(zc.x, 0.f), mulni(G));
  }
}

// ---------- fused conv1+conv2, one (b,d) channel per block, 9-barrier schedule
__global__ __launch_bounds__(512, 4) void k_conv12(
    const float2* __restrict__ Hs, const float2* __restrict__ V0s,
    const float* __restrict__ x0c, const float* __restrict__ x1c, const float* __restrict__ xLc,
    const float* __restrict__ hyb, float* __restrict__ v2, const float2* __restrict__ tw) {
  __shared__ float2 Z[NSLOT4];
  const int b = blockIdx.x >> 10, d = blockIdx.x & 1023;
  const int tid = threadIdx.x;
  const float2* H0 = Hs + (size_t)d * KBINS;
  const float2* H1 = Hs + (size_t)(DD + d) * KBINS;
  const float2* V = V0s + (size_t)b * KBINS;
  const float2* g0 = (const float2*)(x0c + (size_t)b * LL);
  const float2* g1 = (const float2*)(x1c + (size_t)b * LL);
  const float2* v0 = (const float2*)(xLc + (size_t)b * LL);
  // ---- ISSUE-EARLY: gate1 operand loads (used after FFT-A)
  float2 gg0[4], vv0[4];
#pragma unroll
  for (int k = 0; k < 4; ++k) {
    int j = tid + 512 * k;
    gg0[k] = g0[j];
    vv0[k] = v0[j];
  }
  // ---- product1 (Y = V*H0) + inverse twist + bit-rev scatter
#pragma unroll
  for (int gi = 0; gi < 4; ++gi) {
    int k = tid + gi * 512;  // 0..2047
    int m = N4 - k;          // 2049..4096
    float2 Yk = cmul(V[k], H0[k]);
    float2 Ym = cmul(V[m], H0[m]);
    float2 B = conjf(Ym);
    float2 E = make_float2(0.5f * (Yk.x + B.x), 0.5f * (Yk.y + B.y));
    float2 F = make_float2(0.5f * (Yk.x - B.x), 0.5f * (Yk.y - B.y));
    float2 O = cmul(conjf(tw[k]), F);
    float2 iO = mulpi(O);
    Z[SLT(brev12(k))] = cadd(E, iO);
    if (k > 0) Z[SLT(brev12(m))] = conjf(csub(E, iO));
  }
  if (tid == 0) {
    float2 A = cmul(V[2048], H0[2048]);
    float2 F = make_float2(0.f, A.y);
    float2 O = cmul(conjf(tw[2048]), F);
    Z[SLT(brev12(2048))] = cadd(make_float2(A.x, 0.f), mulpi(O));
  }
  __syncthreads();                       // b1
  fft4k_01<true>(Z, tw);
  __syncthreads();                       // b2
  float2 dA[8];
  fft4k_p3<true>(Z, tw, dA);             // time samples z[tid+512k] in regs
  // ---- gate1 in regs (only k<4: first 4096 reals of v1)
  const float bd0 = hyb[d], bd1 = hyb[DD + d];
  float2 vsave[4];
#pragma unroll
  for (int k = 0; k < 4; ++k) {
    vsave[k] = make_float2(gg0[k].x * fmaf(dA[k].x, INV4, bd0 * vv0[k].x),
                           gg0[k].y * fmaf(dA[k].y, INV4, bd0 * vv0[k].y));
  }
  __syncthreads();                       // b3 (all p3 reads complete)
#pragma unroll
  for (int k = 0; k < 4; ++k) {
    int j = tid + 512 * k;
    int r = brev12(j);                   // even
    Z[SLT(r)] = vsave[k];
    Z[SLT(r + 1)] = make_float2(0.f, 0.f);
  }
  __syncthreads();                       // b4
  fft4k_01<false>(Z, tw);
  __syncthreads();                       // b5
  float2 dB[8];
  fft4k_p3<false>(Z, tw, dB);
#pragma unroll
  for (int k = 0; k < 8; ++k) Z[SLT(tid + 512 * k)] = dB[k];  // own slots: race-free
  __syncthreads();                       // b6
  // ---- ISSUE-EARLY: gate2 operand loads (used after FFT-C)
  float2 gg1[4];
#pragma unroll
  for (int k = 0; k < 4; ++k) gg1[k] = g1[tid + 512 * k];
  // ---- fwd twist + product2 (Y = X*H1) + inverse twist, in regs
  float2 zpk[4], zpm[4], z2048;
#pragma unroll
  for (int gi = 0; gi < 4; ++gi) {
    int k = tid + gi * 512;
    int m = N4 - k;
    float2 zk = Z[SLT(k)];
    float2 zm = Z[SLT(m & (N4 - 1))];
    float2 B = conjf(zm);
    float2 E = make_float2(0.5f * (zk.x + B.x), 0.5f * (zk.y + B.y));
    float2 F = make_float2(0.5f * (zk.x - B.x), 0.5f * (zk.y - B.y));
    float2 wk = tw[k];
    float2 G = cmul(wk, F);
    float2 WO = mulni(G);
    float2 Xk = cadd(E, WO);
    float2 Xm = conjf(csub(E, WO));
    float2 Yk = cmul(Xk, H1[k]);
    float2 Ym = cmul(Xm, H1[m]);
    float2 B2 = conjf(Ym);
    float2 E2 = make_float2(0.5f * (Yk.x + B2.x), 0.5f * (Yk.y + B2.y));
    float2 F2 = make_float2(0.5f * (Yk.x - B2.x), 0.5f * (Yk.y - B2.y));
    float2 O2 = cmul(conjf(wk), F2);
    float2 iO2 = mulpi(O2);
    zpk[gi] = cadd(E2, iO2);
    zpm[gi] = conjf(csub(E2, iO2));
  }
  if (tid == 0) {
    float2 zc = Z[SLT(2048)];
    float2 F = make_float2(0.f, zc.y);
    float2 G = cmul(tw[2048], F);
    float2 Xk = cadd(make_float2(zc.x, 0.f), mulni(G));
    float2 Y = cmul(Xk, H1[2048]);
    float2 F2 = make_float2(0.f, Y.y);
    float2 O2 = cmul(conjf(tw[2048]), F2);
    z2048 = cadd(make_float2(Y.x, 0.f), mulpi(O2));
  }
  __syncthreads();                       // b7 (reads done before scatter)
#pragma unroll
  for (int gi = 0; gi < 4; ++gi) {
    int k = tid + gi * 512;
    Z[SLT(brev12(k))] = zpk[gi];
    if (k > 0) Z[SLT(brev12(N4 - k))] = zpm[gi];
  }
  if (tid == 0) Z[SLT(brev12(2048))] = z2048;
  __syncthreads();                       // b8
  fft4k_01<true>(Z, tw);
  __syncthreads();                       // b9
  float2 dC[8];
  fft4k_p3<true>(Z, tw, dC);
  // ---- gate2 + store v2 (only k<4 needed)
  float2* out2 = (float2*)(v2 + ((size_t)b * DD + d) * LL);
#pragma unroll
  for (int k = 0; k < 4; ++k) {
    int j = tid + 512 * k;
    out2[j] = make_float2(gg1[k].x * fmaf(dC[k].x, INV4, bd1 * vsave[k].x),
                          gg1[k].y * fmaf(dC[k].y, INV4, bd1 * vsave[k].y));
  }
}

// -------------------------------------------- y[b][l][d] = u + v2^T (LDS tile transpose)
__global__ __launch_bounds__(256) void k_transpose_add(const float* __restrict__ v2,
                                                       const float* __restrict__ u,
                                                       float* __restrict__ y) {
  __shared__ float T[64][65];
  const int bid = blockIdx.x;
  const int lt = bid & 63, dt = (bid >> 6) & 15, b = bid >> 10;
  const int t = threadIdx.x;
  const int tdr = t >> 2, lc0 = (t & 3) * 16;
  const float* vp = v2 + ((size_t)(b * DD + dt * 64 + tdr)) * LL + lt * 64 + lc0;
#pragma unroll
  for (int q = 0; q < 4; ++q) {
    float4 vv = ((const float4*)vp)[q];
    T[tdr][lc0 + 4 * q + 0] = vv.x;
    T[tdr][lc0 + 4 * q + 1] = vv.y;
    T[tdr][lc0 + 4 * q + 2] = vv.z;
    T[tdr][lc0 + 4 * q + 3] = vv.w;
  }
  __syncthreads();
  const int dc = t & 63, lg = t >> 6;
#pragma unroll
  for (int lr0 = 0; lr0 < 64; lr0 += 4) {
    int lr = lr0 + lg;
    size_t idx = ((size_t)b * LL + lt * 64 + lr) * DD + dt * 64 + dc;
    y[idx] = u[idx] + T[dc][lr];
  }
}

// ----------------------------------------------------- LN2 -> bf16 (wave per row)
__global__ __launch_bounds__(256) void k_ln2(const float* __restrict__ y,
                                             const float* __restrict__ w,
                                             const float* __restrict__ bb,
                                             unsigned short* __restrict__ yln) {
  const int wid = threadIdx.x >> 6, lane = threadIdx.x & 63;
  const size_t r = (size_t)blockIdx.x * 4 + wid;
  const float* yr = y + r * DD;
  float4 v[4];
  float s = 0.f, sq = 0.f;
#pragma unroll
  for (int c = 0; c < 4; ++c) {
    v[c] = ((const float4*)yr)[lane + 64 * c];
    s += v[c].x + v[c].y + v[c].z + v[c].w;
    sq += v[c].x * v[c].x + v[c].y * v[c].y + v[c].z * v[c].z + v[c].w * v[c].w;
  }
  for (int m = 1; m < 64; m <<= 1) { s += __shfl_xor(s, m); sq += __shfl_xor(sq, m); }
  const float mean = s * (1.0f / DD);
  const float var = sq * (1.0f / DD) - mean * mean;
  const float rs = rsqrtf(var + 1e-5f);
#pragma unroll
  for (int c = 0; c < 4; ++c) {
    int i4 = lane + 64 * c;
    float4 wv = ((const float4*)w)[i4];
    float4 bv = ((const float4*)bb)[i4];
    ushort4 o;
    o.x = f2bf((v[c].x - mean) * rs * wv.x + bv.x);
    o.y = f2bf((v[c].y - mean) * rs * wv.y + bv.y);
    o.z = f2bf((v[c].z - mean) * rs * wv.z + bv.z);
    o.w = f2bf((v[c].w - mean) * rs * wv.w + bv.w);
    ((ushort4*)(yln + r * DD))[i4] = o;
  }
}

// --------------- final GEMM: out = yln @ fcw^T + fcb + y  (bf16 MFMA, fp32 out, BK=64)
#define GBM 128
#define GBN 128
#define GBK 64
#if USE_GLOAD_LDS
#define LDK 64   // linear LDS: required by global_load_lds (wave-uniform base + lane*16)
#else
#define LDK 72   // padded reg-staging fallback
#endif

__global__ __launch_bounds__(256) void k_gemm(const short* __restrict__ A,
                                              const short* __restrict__ Bw,
                                              const float* __restrict__ fcb,
                                              const float* __restrict__ yy,
                                              float* __restrict__ out) {
  __shared__ short As[GBM * LDK];
  __shared__ short Bs[GBN * LDK];
  const int t = threadIdx.x;
  const int bm = blockIdx.x & 127;
  const int bn = blockIdx.x >> 7;
  const int wave = t >> 6, lane = t & 63;
  const int wr = wave >> 1, wc = wave & 1;
  const int rrow = lane & 15, kb = (lane >> 4) * 8;

  f32x4 acc[4][4];
#pragma unroll
  for (int i = 0; i < 4; ++i)
#pragma unroll
    for (int j = 0; j < 4; ++j) acc[i][j] = (f32x4){0.f, 0.f, 0.f, 0.f};

  const size_t abase = (size_t)(bm * GBM) * 1024;
  const size_t bbase = (size_t)(bn * GBN) * 1024;

  for (int k0 = 0; k0 < 1024; k0 += GBK) {
#if USE_GLOAD_LDS
    {
      const int r0 = wave * 32;
      const int lrow = lane >> 3, loff = (lane & 7) * 8;
#pragma unroll
      for (int q = 0; q < 4; ++q) {
        const int row = r0 + 8 * q + lrow;
        __builtin_amdgcn_global_load_lds(
            (const __attribute__((address_space(1))) void*)(A + abase + (size_t)row * 1024 + k0 + loff),
            (__attribute__((address_space(3))) void*)&As[(r0 + 8 * q) * LDK], 16, 0, 0);
        __builtin_amdgcn_global_load_lds(
            (const __attribute__((address_space(1))) void*)(Bw + bbase + (size_t)row * 1024 + k0 + loff),
            (__attribute__((address_space(3))) void*)&Bs[(r0 + 8 * q) * LDK], 16, 0, 0);
      }
    }
#else
#pragma unroll
    for (int c = 0; c < 4; ++c) {
      int chunk = c * 256 + t;
      int row = chunk >> 3, off = (chunk & 7) * 8;
      s16x8 av = *(const s16x8*)(A + abase + (size_t)row * 1024 + k0 + off);
      *(s16x8*)&As[row * LDK + off] = av;
      s16x8 bv = *(const s16x8*)(Bw + bbase + (size_t)row * 1024 + k0 + off);
      *(s16x8*)&Bs[row * LDK + off] = bv;
    }
#endif
    __syncthreads();
    s16x8 af[2][4], bfr[2][4];
#pragma unroll
    for (int ks = 0; ks < 2; ++ks) {
#pragma unroll
      for (int mr = 0; mr < 4; ++mr)
        af[ks][mr] = *(const s16x8*)&As[(wr * 64 + mr * 16 + rrow) * LDK + ks * 32 + kb];
#pragma unroll
      for (int nc = 0; nc < 4; ++nc)
        bfr[ks][nc] = *(const s16x8*)&Bs[(wc * 64 + nc * 16 + rrow) * LDK + ks * 32 + kb];
    }
#pragma unroll
    for (int ks = 0; ks < 2; ++ks)
#pragma unroll
      for (int mr = 0; mr < 4; ++mr)
#pragma unroll
        for (int nc = 0; nc < 4; ++nc)
          acc[mr][nc] = __builtin_amdgcn_mfma_f32_16x16x32_bf16(af[ks][mr], bfr[ks][nc],
                                                                acc[mr][nc], 0, 0, 0);
    __syncthreads();
  }
  const int cg = lane >> 4, cr = lane & 15;
#pragma unroll
  for (int mr = 0; mr < 4; ++mr)
#pragma unroll
    for (int nc = 0; nc < 4; ++nc) {
      f32x4 a = acc[mr][nc];
      int col = bn * GBN + wc * 64 + nc * 16 + cr;
#pragma unroll
      for (int q = 0; q < 4; ++q) {
        int row = bm * GBM + wr * 64 + mr * 16 + cg * 4 + q;
        size_t idx = (size_t)row * 1024 + col;
        out[idx] = a[q] + fcb[col] + yy[idx];
      }
    }
}

// ============================================================== launcher
extern "C" void kernel_launch(void* const* d_in, const int* in_sizes, int n_in,
                              void* d_out, int out_size, void* d_ws, size_t ws_size,
                              hipStream_t stream) {
  const float* u      = (const float*)d_in[0];
  const float* n1w    = (const float*)d_in[1];
  const float* n1b    = (const float*)d_in[2];
  const float* projw  = (const float*)d_in[3];
  const float* projb  = (const float*)d_in[4];
  const float* convw  = (const float*)d_in[5];
  const float* convb  = (const float*)d_in[6];
  const float* pos_t  = (const float*)d_in[7];
  const float* pos_z  = (const float*)d_in[8];
  const float* w0     = (const float*)d_in[9];
  const float* b0     = (const float*)d_in[10];
  const float* f0     = (const float*)d_in[11];
  const float* w1     = (const float*)d_in[12];
  const float* b1     = (const float*)d_in[13];
  const float* f1     = (const float*)d_in[14];
  const float* w2     = (const float*)d_in[15];
  const float* b2     = (const float*)d_in[16];
  const float* f2     = (const float*)d_in[17];
  const float* wout   = (const float*)d_in[18];
  const float* alphas = (const float*)d_in[19];
  const float* hyb    = (const float*)d_in[20];
  const float* n2w    = (const float*)d_in[21];
  const float* n2b    = (const float*)d_in[22];
  const float* fcw    = (const float*)d_in[23];
  const float* fcb    = (const float*)d_in[24];

  char* wsb = (char*)d_ws;
  size_t off = 0;
  auto alloc = [&](size_t bytes) -> void* {
    off = (off + 255) & ~(size_t)255;
    void* p = wsb + off;
    off += bytes;
    return p;
  };
  float2* tw    = (float2*)alloc(sizeof(float2) * 4096);
  float*  xp0   = (float*)alloc(sizeof(float) * NB * LL);
  float*  xp1   = (float*)alloc(sizeof(float) * NB * LL);
  float*  xpL   = (float*)alloc(sizeof(float) * NB * LL);
  float*  x0c   = (float*)alloc(sizeof(float) * NB * LL);
  float*  x1c   = (float*)alloc(sizeof(float) * NB * LL);
  float*  xLc   = (float*)alloc(sizeof(float) * NB * LL);
  float*  hid2T = (float*)alloc(sizeof(float) * 64 * LL);
  float2* Hs    = (float2*)alloc(sizeof(float2) * 2 * DD * KBINS);   // 67.1 MB
  float2* V0s   = (float2*)alloc(sizeof(float2) * NB * KBINS);
  float*  v2    = (float*)alloc(sizeof(float) * NB * DD * LL);       // 64 MB
  unsigned short* fcwb = (unsigned short*)alloc(sizeof(unsigned short) * DD * DD);
  float*          y   = (float*)Hs;           // overlay: Hs dead after k_conv12
  unsigned short* yln = (unsigned short*)v2;  // overlay: v2 dead after transpose
  float*          h   = v2;                   // overlay: filter bank dead before conv12
  (void)ws_size; (void)in_sizes; (void)n_in; (void)out_size;

  k_lnproj_ffn<<<(NB * LL) / 4 + LL / 16, 256, 0, stream>>>(
      u, n1w, n1b, projw, projb, xp0, xp1, xpL,
      pos_z, w0, b0, f0, w1, b1, f1, w2, b2, f2, hid2T);
  k_tapconv_prep<<<64 + 16 + (DD * DD / 4) / 256, 256, 0, stream>>>(
      xp0, xp1, xpL, convw, convb, x0c, x1c, xLc, tw, fcw, fcwb);
  k_filter_gemm<<<512, 256, 0, stream>>>(hid2T, wout, alphas, pos_t, h);
  k_fft_filters<<<2048 + NB, 512, 0, stream>>>(h, xLc, Hs, V0s, tw);
  k_conv12<<<NB * DD, 512, 0, stream>>>(Hs, V0s, x0c, x1c, xLc, hyb, v2, tw);
  k_transpose_add<<<4096, 256, 0, stream>>>(v2, u, y);
  k_ln2<<<(NB * LL) / 4, 256, 0, stream>>>(y, n2w, n2b, yln);
  k_gemm<<<(16384 / GBM) * (1024 / GBN), 256, 0, stream>>>((const short*)yln, (const short*)fcwb,
                                                           fcb, y, (float*)d_out);
}